// Round 1
// baseline (1032.255 us; speedup 1.0000x reference)
//
#include <hip/hip_runtime.h>
#include <stdint.h>

#define NG   8
#define BT   4096
#define DIN  1024
#define DHID 2048
#define DOUT 1024

typedef __bf16 bf16x8 __attribute__((ext_vector_type(8)));
typedef float  f32x4  __attribute__((ext_vector_type(4)));

__device__ __forceinline__ unsigned short f2bf(float f) {
    union { float f; unsigned u; } v; v.f = f;
    // round-to-nearest-even fp32 -> bf16
    return (unsigned short)((v.u + 0x7fffu + ((v.u >> 16) & 1u)) >> 16);
}

// -------- Kernel 1: hidden[gl][b][h] = silu(x@Wg) * (x@Wu), stored bf16 --------
__global__ __launch_bounds__(256, 2)
void k_gateup(const float* __restrict__ x,
              const float* __restrict__ wg,
              const float* __restrict__ wu,
              unsigned short* __restrict__ hid,
              int g0) {
    const int HT = DHID / 128;   // 16
    const int MT = BT / 128;     // 32
    int bid = blockIdx.x;
    int ht = bid % HT;
    int mt = (bid / HT) % MT;
    int gl = bid / (HT * MT);
    int g  = g0 + gl;

    __shared__ unsigned short As[128][40];   // [row(m)][k], stride 40 -> 80B rows (16B aligned)
    __shared__ unsigned short Bg[128][40];   // [col(h)][k]
    __shared__ unsigned short Bu[128][40];

    int tid  = threadIdx.x;
    int lane = tid & 63;
    int wave = tid >> 6;
    int quad = lane >> 4;
    int l16  = lane & 15;
    int wm = (wave >> 1) * 64;
    int wn = (wave & 1) * 64;

    f32x4 ag[4][4], au[4][4];
    #pragma unroll
    for (int i = 0; i < 4; i++)
        #pragma unroll
        for (int j = 0; j < 4; j++) {
            ag[i][j] = (f32x4){0.f, 0.f, 0.f, 0.f};
            au[i][j] = (f32x4){0.f, 0.f, 0.f, 0.f};
        }

    const int bh  = tid & 127;   // B staging: output column within tile
    const int kcb = tid >> 7;    // 0..1

    const float* xbase  = x  + ((size_t)(mt * 128) * NG + g) * DIN;
    const float* wgbase = wg + (size_t)g * DIN * DHID + (size_t)ht * 128;
    const float* wubase = wu + (size_t)g * DIN * DHID + (size_t)ht * 128;

    for (int k0 = 0; k0 < DIN; k0 += 32) {
        __syncthreads();
        // ---- stage A: 128 rows x 32 k, fp32 -> bf16, rows strided by NG in x ----
        #pragma unroll
        for (int i = 0; i < 4; i++) {
            int s = tid + 256 * i;
            int row = s >> 3, c4 = s & 7;
            const float4 v = *(const float4*)(xbase + (size_t)row * (NG * DIN) + k0 + c4 * 4);
            ushort4 h;
            h.x = f2bf(v.x); h.y = f2bf(v.y); h.z = f2bf(v.z); h.w = f2bf(v.w);
            *(ushort4*)&As[row][c4 * 4] = h;
        }
        // ---- stage B: transpose [k][h] -> [h][k], fp32 -> bf16, both weights ----
        #pragma unroll
        for (int i = 0; i < 4; i++) {
            int kc = kcb + 2 * i;  // 0..7
            const float* gp = wgbase + (size_t)(k0 + kc * 4) * DHID + bh;
            ushort4 hg;
            hg.x = f2bf(gp[0]); hg.y = f2bf(gp[DHID]);
            hg.z = f2bf(gp[2 * DHID]); hg.w = f2bf(gp[3 * DHID]);
            *(ushort4*)&Bg[bh][kc * 4] = hg;
            const float* up = wubase + (size_t)(k0 + kc * 4) * DHID + bh;
            ushort4 hu;
            hu.x = f2bf(up[0]); hu.y = f2bf(up[DHID]);
            hu.z = f2bf(up[2 * DHID]); hu.w = f2bf(up[3 * DHID]);
            *(ushort4*)&Bu[bh][kc * 4] = hu;
        }
        __syncthreads();

        bf16x8 af[4], bgf[4], buf_[4];
        #pragma unroll
        for (int mi = 0; mi < 4; mi++)
            af[mi] = *(const bf16x8*)&As[wm + mi * 16 + l16][quad * 8];
        #pragma unroll
        for (int ni = 0; ni < 4; ni++) {
            bgf[ni]  = *(const bf16x8*)&Bg[wn + ni * 16 + l16][quad * 8];
            buf_[ni] = *(const bf16x8*)&Bu[wn + ni * 16 + l16][quad * 8];
        }
        #pragma unroll
        for (int mi = 0; mi < 4; mi++)
            #pragma unroll
            for (int ni = 0; ni < 4; ni++) {
                ag[mi][ni] = __builtin_amdgcn_mfma_f32_16x16x32_bf16(af[mi], bgf[ni],  ag[mi][ni], 0, 0, 0);
                au[mi][ni] = __builtin_amdgcn_mfma_f32_16x16x32_bf16(af[mi], buf_[ni], au[mi][ni], 0, 0, 0);
            }
    }

    // ---- epilogue: silu(gate)*up -> bf16 hidden, group-major layout ----
    unsigned short* hb = hid + (size_t)gl * BT * DHID;
    #pragma unroll
    for (int mi = 0; mi < 4; mi++)
        #pragma unroll
        for (int ni = 0; ni < 4; ni++)
            #pragma unroll
            for (int r = 0; r < 4; r++) {
                int row = mt * 128 + wm + mi * 16 + quad * 4 + r;   // b_local
                int col = ht * 128 + wn + ni * 16 + l16;            // h
                float gv = ag[mi][ni][r];
                float uv = au[mi][ni][r];
                float sv = gv / (1.f + __expf(-gv));
                hb[(size_t)row * DHID + col] = f2bf(sv * uv);
            }
}

// -------- Kernel 2: out = hidden @ Wd, fp32 output in token-interleaved rows --------
__global__ __launch_bounds__(256, 2)
void k_down(const unsigned short* __restrict__ hid,
            const float* __restrict__ wd,
            float* __restrict__ out,
            int g0) {
    const int OT = DOUT / 128;   // 8
    const int MT = BT / 128;     // 32
    int bid = blockIdx.x;
    int ot = bid % OT;
    int mt = (bid / OT) % MT;
    int gl = bid / (OT * MT);
    int g  = g0 + gl;

    __shared__ unsigned short As[128][40];
    __shared__ unsigned short Bs[128][40];

    int tid  = threadIdx.x;
    int lane = tid & 63;
    int wave = tid >> 6;
    int quad = lane >> 4;
    int l16  = lane & 15;
    int wm = (wave >> 1) * 64;
    int wn = (wave & 1) * 64;

    f32x4 ac[4][4];
    #pragma unroll
    for (int i = 0; i < 4; i++)
        #pragma unroll
        for (int j = 0; j < 4; j++)
            ac[i][j] = (f32x4){0.f, 0.f, 0.f, 0.f};

    const int bh  = tid & 127;
    const int kcb = tid >> 7;

    const unsigned short* hbase = hid + ((size_t)gl * BT + mt * 128) * DHID;
    const float* wdbase = wd + (size_t)g * DHID * DOUT + (size_t)ot * 128;

    for (int k0 = 0; k0 < DHID; k0 += 32) {
        __syncthreads();
        // ---- stage A: hidden is already bf16, pure 16B copies ----
        #pragma unroll
        for (int i = 0; i < 2; i++) {
            int s = tid + 256 * i;
            int row = s >> 2, c8 = s & 3;
            uint4 v = *(const uint4*)(hbase + (size_t)row * DHID + k0 + c8 * 8);
            *(uint4*)&As[row][c8 * 8] = v;
        }
        // ---- stage B: transpose down weights, fp32 -> bf16 ----
        #pragma unroll
        for (int i = 0; i < 4; i++) {
            int kc = kcb + 2 * i;
            const float* dp = wdbase + (size_t)(k0 + kc * 4) * DOUT + bh;
            ushort4 hd;
            hd.x = f2bf(dp[0]); hd.y = f2bf(dp[DOUT]);
            hd.z = f2bf(dp[2 * DOUT]); hd.w = f2bf(dp[3 * DOUT]);
            *(ushort4*)&Bs[bh][kc * 4] = hd;
        }
        __syncthreads();

        bf16x8 af[4], bf[4];
        #pragma unroll
        for (int mi = 0; mi < 4; mi++)
            af[mi] = *(const bf16x8*)&As[wm + mi * 16 + l16][quad * 8];
        #pragma unroll
        for (int ni = 0; ni < 4; ni++)
            bf[ni] = *(const bf16x8*)&Bs[wn + ni * 16 + l16][quad * 8];
        #pragma unroll
        for (int mi = 0; mi < 4; mi++)
            #pragma unroll
            for (int ni = 0; ni < 4; ni++)
                ac[mi][ni] = __builtin_amdgcn_mfma_f32_16x16x32_bf16(af[mi], bf[ni], ac[mi][ni], 0, 0, 0);
    }

    // ---- epilogue: fp32 store, token row = b_local*NG + g ----
    #pragma unroll
    for (int mi = 0; mi < 4; mi++)
        #pragma unroll
        for (int ni = 0; ni < 4; ni++)
            #pragma unroll
            for (int r = 0; r < 4; r++) {
                int row = mt * 128 + wm + mi * 16 + quad * 4 + r;   // b_local
                int col = ot * 128 + wn + ni * 16 + l16;            // o
                out[((size_t)row * NG + g) * DOUT + col] = ac[mi][ni][r];
            }
}

extern "C" void kernel_launch(void* const* d_in, const int* in_sizes, int n_in,
                              void* d_out, int out_size, void* d_ws, size_t ws_size,
                              hipStream_t stream) {
    const float* x  = (const float*)d_in[0];
    const float* wg = (const float*)d_in[1];
    const float* wu = (const float*)d_in[2];
    const float* wd = (const float*)d_in[3];
    float* out = (float*)d_out;
    unsigned short* hid = (unsigned short*)d_ws;

    const size_t full = (size_t)NG * BT * DHID * sizeof(unsigned short);  // 134 MB
    if (ws_size >= full) {
        k_gateup<<<dim3(NG * (BT / 128) * (DHID / 128)), dim3(256), 0, stream>>>(x, wg, wu, hid, 0);
        k_down  <<<dim3(NG * (BT / 128) * (DOUT / 128)), dim3(256), 0, stream>>>(hid, wd, out, 0);
    } else {
        // per-group fallback: reuse one group's hidden buffer (16.8 MB)
        for (int g = 0; g < NG; g++) {
            k_gateup<<<dim3((BT / 128) * (DHID / 128)), dim3(256), 0, stream>>>(x, wg, wu, hid, g);
            k_down  <<<dim3((BT / 128) * (DOUT / 128)), dim3(256), 0, stream>>>(hid, wd, out, g);
        }
    }
}